// Round 10
// baseline (3992.688 us; speedup 1.0000x reference)
//
#include <hip/hip_runtime.h>
#include <stdint.h>

// Problem constants (fixed by setup_inputs)
#define Bn 256
#define Hn 768
#define Tn 128
#define KS 24      // Hn/32 ksteps
#define CBn 48     // col-blocks (j-tiles of 16 hidden units x 3 gates)
#define NTHR 1024  // 16 waves: wave -> (rg = wave>>2, mt = wave&3)
#define SMEM_BYTES 147456  // W slice hi+lo in LDS
#define SUBW 64    // words between sub-counters (256B: separate cache lines)

typedef __attribute__((ext_vector_type(8))) short short8;   // 8 bf16
typedef __attribute__((ext_vector_type(4))) float floatx4;  // mfma C/D

static __device__ __forceinline__ unsigned short f2bf(float f) {
  unsigned int x = __float_as_uint(f);
  x += 0x7fffu + ((x >> 16) & 1u);
  return (unsigned short)(x >> 16);
}
static __device__ __forceinline__ float bf2f(unsigned short u) {
  return __uint_as_float(((unsigned int)u) << 16);
}

// ---------------------------------------------------------------------------
// Swizzle W_hh (2304x768 fp32 row-major) into B-fragment-ordered bf16 hi/lo
// chunk planes. Chunk (tile = g*48+jt, kstep): 1 KiB, lane L holds
// W[n0+(L&15)][k0+(L>>4)*8 .. +8]  (B[k][n] frag for mfma_f32_16x16x32_bf16).
// ---------------------------------------------------------------------------
__global__ void swz_w(const float* __restrict__ W,
                      unsigned short* __restrict__ whi,
                      unsigned short* __restrict__ wlo) {
  int i = blockIdx.x * blockDim.x + threadIdx.x;
  if (i >= 2304 * (Hn / 8)) return;
  int n  = i / (Hn / 8);
  int k0 = (i % (Hn / 8)) * 8;
  int tile = n >> 4, kstep = k0 >> 5;
  int lane = (n & 15) + (((k0 >> 3) & 3) << 4);
  size_t off = ((size_t)(tile * KS + kstep)) * 512 + (size_t)lane * 8;
  const float* src = W + (size_t)n * Hn + k0;
  short8 h8, l8;
#pragma unroll
  for (int q = 0; q < 8; ++q) {
    float w = src[q];
    unsigned short hb = f2bf(w);
    h8[q] = (short)hb;
    l8[q] = (short)f2bf(w - bf2f(hb));
  }
  *(short8*)(whi + off) = h8;
  *(short8*)(wlo + off) = l8;
}

// ---------------------------------------------------------------------------
// Init: h0 planes (bf16 hi/lo) from context; zero ddot and barrier counters.
// hbase layout: [hhi0 | hlo0 | hhi1 | hlo1], each Bn*Hn elements.
// ---------------------------------------------------------------------------
__global__ void init_h(const float* __restrict__ ctx,
                       unsigned short* __restrict__ hbase,
                       float* __restrict__ ddot, unsigned* __restrict__ cnt) {
  int i = blockIdx.x * blockDim.x + threadIdx.x;
  if (i < Bn * Hn) {
    float c = ctx[i];
    unsigned short hb = f2bf(c);
    hbase[i] = hb;                       // hhi0
    hbase[Bn * Hn + i] = f2bf(c - bf2f(hb));  // hlo0
  }
  if (i < Tn * Bn) ddot[i] = 0.f;
  if (i < 8 * SUBW) cnt[i] = 0u;
}

// ---------------------------------------------------------------------------
// Persistent GRU — R7-proven protocol, 4x fewer fencing participants.
// Grid = 48 blocks x 1024 threads (1 block/CU). Block cb owns j-tile cb
// (16 hidden x 3 gates, W slice in LDS) for ALL 256 rows: wave w handles
// row-group w>>2, m-tile w&3 — identical per-wave work to R7. Per step:
// normal h stores -> __syncthreads (vmcnt drain) -> ONE release-RMW arrive
// per block (48/step instead of 192) -> relaxed-load tree poll -> ONE
// acquire (inv) per block -> normal loads. h_old in registers.
// ---------------------------------------------------------------------------
__global__ __launch_bounds__(NTHR, 4) void gru_persist(
    const unsigned short* __restrict__ whi, const unsigned short* __restrict__ wlo,
    unsigned short* hbase,
    const float* __restrict__ bias_ih, const float* __restrict__ bias_hh,
    const float* __restrict__ fc_w, const float* __restrict__ ctx,
    float* __restrict__ ddot, unsigned* __restrict__ cnt) {
  extern __shared__ char smem[];
  unsigned short* lds_w = (unsigned short*)smem;  // 144 chunks x 1 KiB

  const int cb = blockIdx.x;      // 0..47
  const int tid = threadIdx.x;
  const int lane = tid & 63;
  const int wave = tid >> 6;      // 0..15: rg = wave>>2, mt = wave&3
  const int ln15 = lane & 15, quad = lane >> 4;
  const int j0 = cb * 16;

  // ---- stage W slice into LDS: chunk c = (g*24+ks)*2+plane ----
  for (int u = tid; u < 144 * 64; u += NTHR) {
    int c = u >> 6, w = u & 63;
    int plane = c & 1;
    int ks = (c >> 1) % KS;
    int g  = c / (2 * KS);
    const unsigned short* src =
        (plane ? wlo : whi) + ((size_t)((g * CBn + cb) * KS + ks)) * 512 + (size_t)w * 8;
    *(short8*)(lds_w + (size_t)c * 512 + w * 8) = *(const short8*)src;
  }

  // ---- per-lane constants ----
  const int j = j0 + ln15;
  const float bir = bias_ih[j], biz = bias_ih[Hn + j], bin = bias_ih[2 * Hn + j];
  const float bhr = bias_hh[j], bhz = bias_hh[Hn + j], bhn = bias_hh[2 * Hn + j];
  const float fw = fc_w[j];
  const int mrow0 = wave * 16;  // wave's 16 rows (0..255 across 16 waves)

  // h_old in registers: thread owns rows mrow0+quad*4+i, col j, forever
  float hold[4];
#pragma unroll
  for (int i = 0; i < 4; ++i)
    hold[i] = ctx[(size_t)(mrow0 + quad * 4 + i) * Hn + j];

  const size_t N = (size_t)Bn * Hn;
  unsigned short* HHI[2] = {hbase, hbase + 2 * N};
  unsigned short* HLO[2] = {hbase + N, hbase + 3 * N};

  __syncthreads();

  int p = 0;
  for (int t = 0; t < Tn; ++t) {
    const unsigned short* Ah_base = HHI[p] + (size_t)(mrow0 + ln15) * Hn + quad * 8;
    const unsigned short* Al_base = HLO[p] + (size_t)(mrow0 + ln15) * Hn + quad * 8;

    floatx4 acc[3];
#pragma unroll
    for (int g = 0; g < 3; ++g) acc[g] = (floatx4){0.f, 0.f, 0.f, 0.f};

    // chunked (4-kstep) double-buffered A prefetch, full unroll (verbatim R7)
    short8 Abh[2][4], Abl[2][4];
#pragma unroll
    for (int q = 0; q < 4; ++q) {
      Abh[0][q] = *(const short8*)(Ah_base + q * 32);
      Abl[0][q] = *(const short8*)(Al_base + q * 32);
    }
#pragma unroll
    for (int c = 0; c < 6; ++c) {
      const int cur = c & 1, nxt = cur ^ 1;
      if (c < 5) {
#pragma unroll
        for (int q = 0; q < 4; ++q) {
          Abh[nxt][q] = *(const short8*)(Ah_base + ((c + 1) * 4 + q) * 32);
          Abl[nxt][q] = *(const short8*)(Al_base + ((c + 1) * 4 + q) * 32);
        }
      }
#pragma unroll
      for (int kk = 0; kk < 4; ++kk) {
        const int ks = c * 4 + kk;
#pragma unroll
        for (int g = 0; g < 3; ++g) {
          const int cbase = ((g * KS + ks) * 2) * 512 + lane * 8;
          short8 Bh = *(const short8*)(lds_w + cbase);
          short8 Bl = *(const short8*)(lds_w + cbase + 512);
          acc[g] = __builtin_amdgcn_mfma_f32_16x16x32_bf16(Abh[cur][kk], Bh, acc[g], 0, 0, 0);
          acc[g] = __builtin_amdgcn_mfma_f32_16x16x32_bf16(Abl[cur][kk], Bh, acc[g], 0, 0, 0);
          acc[g] = __builtin_amdgcn_mfma_f32_16x16x32_bf16(Abh[cur][kk], Bl, acc[g], 0, 0, 0);
        }
      }
    }

    // ---- register epilogue: gates + h_new + fc partial ----
    float fcv[4];
#pragma unroll
    for (int i = 0; i < 4; ++i) {
      const int r = mrow0 + quad * 4 + i;  // C/D layout: row = quad*4 + i
      float gr = bir + bhr + acc[0][i];
      float gz = biz + bhz + acc[1][i];
      float rr = 1.f / (1.f + __expf(-gr));
      float zz = 1.f / (1.f + __expf(-gz));
      float gn = bin + rr * (acc[2][i] + bhn);
      float nn = 1.f - 2.f / (1.f + __expf(2.f * gn));  // tanh
      float hn = (1.f - zz) * nn + zz * hold[i];
      hold[i] = hn;
      size_t idx = (size_t)r * Hn + j;
      unsigned short hb = f2bf(hn);
      HHI[p ^ 1][idx] = hb;                  // normal 2B stores (R3/R7-proven)
      HLO[p ^ 1][idx] = f2bf(hn - bf2f(hb));
      fcv[i] = hn * fw;
    }
#pragma unroll
    for (int i = 0; i < 4; ++i) {
      fcv[i] += __shfl_xor(fcv[i], 1);
      fcv[i] += __shfl_xor(fcv[i], 2);
      fcv[i] += __shfl_xor(fcv[i], 4);
      fcv[i] += __shfl_xor(fcv[i], 8);
    }
    if (ln15 == 0) {
#pragma unroll
      for (int i = 0; i < 4; ++i)
        atomicAdd(&ddot[t * Bn + mrow0 + quad * 4 + i], fcv[i]);
    }

    // ---- barrier: ONE release arrive + tree poll + ONE acquire per block ----
    __syncthreads();  // all 16 waves' stores drained (vmcnt(0)) before release
    if (tid == 0)
      __hip_atomic_fetch_add(&cnt[(cb >> 3) * SUBW], 1u, __ATOMIC_RELEASE,
                             __HIP_MEMORY_SCOPE_AGENT);
    if (wave == 0) {
      const unsigned tgt = 8u * (unsigned)(t + 1);  // 8 blocks per sub-counter
      while (true) {
        unsigned v = (lane < 6)
            ? __hip_atomic_load(&cnt[lane * SUBW], __ATOMIC_RELAXED,
                                __HIP_MEMORY_SCOPE_AGENT)
            : tgt;
        if (__ballot(v >= tgt) == ~0ull) break;
        __builtin_amdgcn_s_sleep(1);
      }
    }
    if (tid == 0)  // acquire: inv L1/L2 so this block's normal loads see fresh h
      (void)__hip_atomic_load(&cnt[0], __ATOMIC_ACQUIRE, __HIP_MEMORY_SCOPE_AGENT);
    __syncthreads();
    p ^= 1;
  }
}

// ---------------------------------------------------------------------------
// Post: softplus -> inclusive scan over T -> normalize -> assemble output.
// ---------------------------------------------------------------------------
__global__ void post_k(const float* __restrict__ ddot,
                       const float* __restrict__ fc_b,
                       const int* __restrict__ npred, float* __restrict__ out) {
  const int b = blockIdx.x;
  const int t = threadIdx.x;  // 0..127
  __shared__ float s[Tn];
  float x = ddot[(size_t)t * Bn + b] + fc_b[0];
  float sp = (x > 20.f) ? x : log1pf(__expf(x));
  s[t] = sp;
  __syncthreads();
  for (int off = 1; off < Tn; off <<= 1) {
    float v = s[t];
    float add = (t >= off) ? s[t - off] : 0.f;
    __syncthreads();
    s[t] = v + add;
    __syncthreads();
  }
  const int n = npred[b];
  const float last = s[n - 1] + 1e-6f;
  float body = (t < n) ? (s[t] / last) : 0.f;
  float* ob = out + (size_t)b * (Tn + 2);
  ob[1 + t] = body;
  if (t == 0) { ob[0] = 0.f; ob[Tn + 1] = 0.f; }
  __syncthreads();
  if (t == 0) ob[n + 1] = 1.f;
}

// ---------------------------------------------------------------------------
extern "C" void kernel_launch(void* const* d_in, const int* in_sizes, int n_in,
                              void* d_out, int out_size, void* d_ws, size_t ws_size,
                              hipStream_t stream) {
  const float* context   = (const float*)d_in[0];
  // d_in[1] = weight_ih: unused by the reference computation
  const float* weight_hh = (const float*)d_in[2];
  const float* bias_ih   = (const float*)d_in[3];
  const float* bias_hh   = (const float*)d_in[4];
  const float* fc_w      = (const float*)d_in[5];
  const float* fc_b      = (const float*)d_in[6];
  const int*   npred     = (const int*)d_in[7];
  float* out = (float*)d_out;

  char* ws = (char*)d_ws;
  size_t o = 0;
  unsigned short* hbase = (unsigned short*)(ws + o); o += (size_t)4 * Bn * Hn * 2;
  unsigned short* whi   = (unsigned short*)(ws + o); o += (size_t)3 * Hn * Hn * 2;
  unsigned short* wlo   = (unsigned short*)(ws + o); o += (size_t)3 * Hn * Hn * 2;
  float* ddot = (float*)(ws + o); o += (size_t)Tn * Bn * 4;
  unsigned* cntp = (unsigned*)(ws + o); o += (size_t)8 * SUBW * 4;
  // ~8.85 MB of d_ws (R3/R7-proven footprint)

  swz_w<<<dim3((2304 * (Hn / 8) + 255) / 256), dim3(256), 0, stream>>>(weight_hh, whi, wlo);
  init_h<<<dim3((Bn * Hn + 255) / 256), dim3(256), 0, stream>>>(context, hbase, ddot, cntp);

  hipFuncSetAttribute((const void*)gru_persist,
                      hipFuncAttributeMaxDynamicSharedMemorySize, SMEM_BYTES);
  void* kargs[] = {(void*)&whi, (void*)&wlo, (void*)&hbase, (void*)&bias_ih,
                   (void*)&bias_hh, (void*)&fc_w, (void*)&context, (void*)&ddot,
                   (void*)&cntp};
  hipLaunchCooperativeKernel((const void*)gru_persist, dim3(CBn), dim3(NTHR),
                             kargs, SMEM_BYTES, stream);

  post_k<<<dim3(Bn), dim3(Tn), 0, stream>>>(ddot, fc_b, npred, out);
}

// Round 11
// 1934.578 us; speedup vs baseline: 2.0639x; 2.0639x over previous
//
#include <hip/hip_runtime.h>
#include <stdint.h>

// Problem constants (fixed by setup_inputs)
#define Bn 256
#define Hn 768
#define Tn 128
#define KS 24      // Hn/32 ksteps
#define CBn 48     // col-blocks (j-tiles of 16 hidden units x 3 gates)
#define RGn 4      // row-groups of 64 batch rows
#define NTHR 256   // 4 waves; wave w owns m-tile w (16 rows), all gates, full K
#define SMEM_BYTES 147456  // W slice hi+lo in LDS (dynamic)

typedef __attribute__((ext_vector_type(8))) short short8;   // 8 bf16
typedef __attribute__((ext_vector_type(4))) float floatx4;  // mfma C/D

static __device__ __forceinline__ unsigned short f2bf(float f) {
  unsigned int x = __float_as_uint(f);
  x += 0x7fffu + ((x >> 16) & 1u);
  return (unsigned short)(x >> 16);
}
static __device__ __forceinline__ float bf2f(unsigned short u) {
  return __uint_as_float(((unsigned int)u) << 16);
}

// ---------------------------------------------------------------------------
// Swizzle W_hh (2304x768 fp32 row-major) into slice-contiguous B-fragment
// order, bf16 hi/lo interleaved per chunk. Slice cb (147456 B): chunk
// c = (g*24+ks)*2 + plane, 1 KiB each; within a chunk lane L holds
// W[g*768 + cb*16 + (L&15)][ks*32 + (L>>4)*8 .. +8].
// Slice-contiguous => per-step LDS staging is a linear async copy.
// ---------------------------------------------------------------------------
__global__ void swz_w(const float* __restrict__ W,
                      unsigned short* __restrict__ wsw) {
  int i = blockIdx.x * blockDim.x + threadIdx.x;
  if (i >= 2304 * (Hn / 8)) return;
  int n  = i / (Hn / 8);
  int k0 = (i % (Hn / 8)) * 8;
  int g = n / Hn, jj = n % Hn;
  int cb = jj >> 4, l15 = jj & 15;
  int ks = k0 >> 5, k8 = (k0 >> 3) & 3;
  int lane = l15 + 16 * k8;
  unsigned short* slice = wsw + (size_t)cb * 73728;
  size_t offh = ((size_t)((g * KS + ks) * 2 + 0)) * 512 + (size_t)lane * 8;
  size_t offl = ((size_t)((g * KS + ks) * 2 + 1)) * 512 + (size_t)lane * 8;
  const float* src = W + (size_t)n * Hn + k0;
  short8 h8, l8;
#pragma unroll
  for (int q = 0; q < 8; ++q) {
    float w = src[q];
    unsigned short hb = f2bf(w);
    h8[q] = (short)hb;
    l8[q] = (short)f2bf(w - bf2f(hb));
  }
  *(short8*)(slice + offh) = h8;
  *(short8*)(slice + offl) = l8;
}

// ---------------------------------------------------------------------------
// Init: h0 planes (bf16 hi/lo) from context; zero ddot.
// hbase layout: [hhi0 | hlo0 | hhi1 | hlo1], each Bn*Hn elements.
// ---------------------------------------------------------------------------
__global__ void init_h(const float* __restrict__ ctx,
                       unsigned short* __restrict__ hbase,
                       float* __restrict__ ddot) {
  int i = blockIdx.x * blockDim.x + threadIdx.x;
  if (i < Bn * Hn) {
    float c = ctx[i];
    unsigned short hb = f2bf(c);
    hbase[i] = hb;                            // hhi0
    hbase[Bn * Hn + i] = f2bf(c - bf2f(hb));  // hlo0
  }
  if (i < Tn * Bn) ddot[i] = 0.f;
}

// ---------------------------------------------------------------------------
// ONE GRU step per dispatch — coherence via the dispatch boundary (proven
// R1: normal stores -> next-dispatch normal loads, incl. ping-pong reuse).
// Block (cb, rg): stages W slice cb into LDS via async global_load_lds
// (width 16, 36 chunks/wave, drained by the s_waitcnt vmcnt(0) that
// __syncthreads emits), then the R7 K-loop: wave w owns m-tile w (16 rows),
// all 3 gates, full K, split-bf16 (3 MFMAs/product). No fences, no flags.
// ---------------------------------------------------------------------------
__global__ __launch_bounds__(NTHR) void gru_step(
    const unsigned short* __restrict__ wsw,
    const unsigned short* __restrict__ hhi_in,
    const unsigned short* __restrict__ hlo_in,
    unsigned short* __restrict__ hhi_out,
    unsigned short* __restrict__ hlo_out,
    const float* __restrict__ bias_ih, const float* __restrict__ bias_hh,
    const float* __restrict__ fc_w, float* __restrict__ ddot_t) {
  extern __shared__ char smem[];
  unsigned short* lds_w = (unsigned short*)smem;  // 144 chunks x 1 KiB

  const int cb = blockIdx.x;      // 0..47
  const int rg = blockIdx.y;      // 0..3
  const int tid = threadIdx.x;
  const int lane = tid & 63;
  const int wave = tid >> 6;
  const int ln15 = lane & 15, quad = lane >> 4;
  const int j0 = cb * 16;

  // ---- async W staging: wave w stages chunks [36w, 36w+36) ----
  const unsigned short* wsrc = wsw + (size_t)cb * 73728;
  for (int i = 0; i < 36; ++i) {
    const int c = wave * 36 + i;
    __builtin_amdgcn_global_load_lds(
        (const __attribute__((address_space(1))) unsigned int*)(wsrc + (size_t)c * 512 + lane * 8),
        (__attribute__((address_space(3))) unsigned int*)(lds_w + (size_t)c * 512),
        16, 0, 0);
  }

  // ---- per-lane constants ----
  const int j = j0 + ln15;
  const float bir = bias_ih[j], biz = bias_ih[Hn + j], bin = bias_ih[2 * Hn + j];
  const float bhr = bias_hh[j], bhz = bias_hh[Hn + j], bhn = bias_hh[2 * Hn + j];
  const float fw = fc_w[j];
  const int mrow0 = rg * 64 + wave * 16;  // wave's 16 rows

  // h_old loads (epilogue inputs) issued early; latency hidden by GEMM
  unsigned short hoh[4], hol[4];
#pragma unroll
  for (int i = 0; i < 4; ++i) {
    size_t idx = (size_t)(mrow0 + quad * 4 + i) * Hn + j;
    hoh[i] = hhi_in[idx];
    hol[i] = hlo_in[idx];
  }

  const unsigned short* Ah_base = hhi_in + (size_t)(mrow0 + ln15) * Hn + quad * 8;
  const unsigned short* Al_base = hlo_in + (size_t)(mrow0 + ln15) * Hn + quad * 8;

  floatx4 acc[3];
#pragma unroll
  for (int g = 0; g < 3; ++g) acc[g] = (floatx4){0.f, 0.f, 0.f, 0.f};

  // first A chunk prefetch (before the barrier: more latency overlap)
  short8 Abh[2][4], Abl[2][4];
#pragma unroll
  for (int q = 0; q < 4; ++q) {
    Abh[0][q] = *(const short8*)(Ah_base + q * 32);
    Abl[0][q] = *(const short8*)(Al_base + q * 32);
  }

  __syncthreads();  // drains vmcnt(0): W staging + A chunk 0 complete

#pragma unroll
  for (int c = 0; c < 6; ++c) {
    const int cur = c & 1, nxt = cur ^ 1;
    if (c < 5) {
#pragma unroll
      for (int q = 0; q < 4; ++q) {
        Abh[nxt][q] = *(const short8*)(Ah_base + ((c + 1) * 4 + q) * 32);
        Abl[nxt][q] = *(const short8*)(Al_base + ((c + 1) * 4 + q) * 32);
      }
    }
#pragma unroll
    for (int kk = 0; kk < 4; ++kk) {
      const int ks = c * 4 + kk;
#pragma unroll
      for (int g = 0; g < 3; ++g) {
        const int cbase = ((g * KS + ks) * 2) * 512 + lane * 8;
        short8 Bh = *(const short8*)(lds_w + cbase);
        short8 Bl = *(const short8*)(lds_w + cbase + 512);
        acc[g] = __builtin_amdgcn_mfma_f32_16x16x32_bf16(Abh[cur][kk], Bh, acc[g], 0, 0, 0);
        acc[g] = __builtin_amdgcn_mfma_f32_16x16x32_bf16(Abl[cur][kk], Bh, acc[g], 0, 0, 0);
        acc[g] = __builtin_amdgcn_mfma_f32_16x16x32_bf16(Abh[cur][kk], Bl, acc[g], 0, 0, 0);
      }
    }
  }

  // ---- epilogue: gates + h_new + fc partial ----
  float fcv[4];
#pragma unroll
  for (int i = 0; i < 4; ++i) {
    const int r = mrow0 + quad * 4 + i;  // C/D layout: row = quad*4 + i
    float gr = bir + bhr + acc[0][i];
    float gz = biz + bhz + acc[1][i];
    float rr = 1.f / (1.f + __expf(-gr));
    float zz = 1.f / (1.f + __expf(-gz));
    float gn = bin + rr * (acc[2][i] + bhn);
    float nn = 1.f - 2.f / (1.f + __expf(2.f * gn));  // tanh
    float hold = bf2f(hoh[i]) + bf2f(hol[i]);
    float hn = (1.f - zz) * nn + zz * hold;
    size_t idx = (size_t)r * Hn + j;
    unsigned short hb = f2bf(hn);
    hhi_out[idx] = hb;                  // normal stores; CP flushes at boundary
    hlo_out[idx] = f2bf(hn - bf2f(hb));
    fcv[i] = hn * fw;
  }
#pragma unroll
  for (int i = 0; i < 4; ++i) {
    fcv[i] += __shfl_xor(fcv[i], 1);
    fcv[i] += __shfl_xor(fcv[i], 2);
    fcv[i] += __shfl_xor(fcv[i], 4);
    fcv[i] += __shfl_xor(fcv[i], 8);
  }
  if (ln15 == 0) {
#pragma unroll
    for (int i = 0; i < 4; ++i)
      atomicAdd(&ddot_t[mrow0 + quad * 4 + i], fcv[i]);
  }
}

// ---------------------------------------------------------------------------
// Post: softplus -> inclusive scan over T -> normalize -> assemble output.
// ---------------------------------------------------------------------------
__global__ void post_k(const float* __restrict__ ddot,
                       const float* __restrict__ fc_b,
                       const int* __restrict__ npred, float* __restrict__ out) {
  const int b = blockIdx.x;
  const int t = threadIdx.x;  // 0..127
  __shared__ float s[Tn];
  float x = ddot[(size_t)t * Bn + b] + fc_b[0];
  float sp = (x > 20.f) ? x : log1pf(__expf(x));
  s[t] = sp;
  __syncthreads();
  for (int off = 1; off < Tn; off <<= 1) {
    float v = s[t];
    float add = (t >= off) ? s[t - off] : 0.f;
    __syncthreads();
    s[t] = v + add;
    __syncthreads();
  }
  const int n = npred[b];
  const float last = s[n - 1] + 1e-6f;
  float body = (t < n) ? (s[t] / last) : 0.f;
  float* ob = out + (size_t)b * (Tn + 2);
  ob[1 + t] = body;
  if (t == 0) { ob[0] = 0.f; ob[Tn + 1] = 0.f; }
  __syncthreads();
  if (t == 0) ob[n + 1] = 1.f;
}

// ---------------------------------------------------------------------------
extern "C" void kernel_launch(void* const* d_in, const int* in_sizes, int n_in,
                              void* d_out, int out_size, void* d_ws, size_t ws_size,
                              hipStream_t stream) {
  const float* context   = (const float*)d_in[0];
  // d_in[1] = weight_ih: unused by the reference computation
  const float* weight_hh = (const float*)d_in[2];
  const float* bias_ih   = (const float*)d_in[3];
  const float* bias_hh   = (const float*)d_in[4];
  const float* fc_w      = (const float*)d_in[5];
  const float* fc_b      = (const float*)d_in[6];
  const int*   npred     = (const int*)d_in[7];
  float* out = (float*)d_out;

  char* ws = (char*)d_ws;
  size_t o = 0;
  unsigned short* hbase = (unsigned short*)(ws + o); o += (size_t)4 * Bn * Hn * 2;
  unsigned short* wsw   = (unsigned short*)(ws + o); o += (size_t)6 * Hn * Hn * 2;
  float* ddot = (float*)(ws + o); o += (size_t)Tn * Bn * 4;
  // ~8.8 MB of d_ws

  const size_t N = (size_t)Bn * Hn;
  unsigned short* HHI[2] = {hbase, hbase + 2 * N};
  unsigned short* HLO[2] = {hbase + N, hbase + 3 * N};

  swz_w<<<dim3((2304 * (Hn / 8) + 255) / 256), dim3(256), 0, stream>>>(weight_hh, wsw);
  init_h<<<dim3((Bn * Hn + 255) / 256), dim3(256), 0, stream>>>(context, hbase, ddot);

  hipFuncSetAttribute((const void*)gru_step,
                      hipFuncAttributeMaxDynamicSharedMemorySize, SMEM_BYTES);

  int cur = 0;
  for (int t = 0; t < Tn; ++t) {
    gru_step<<<dim3(CBn, RGn), dim3(NTHR), SMEM_BYTES, stream>>>(
        wsw, HHI[cur], HLO[cur], HHI[1 - cur], HLO[1 - cur],
        bias_ih, bias_hh, fc_w, ddot + (size_t)t * Bn);
    cur ^= 1;
  }

  post_k<<<dim3(Bn), dim3(Tn), 0, stream>>>(ddot, fc_b, npred, out);
}